// Round 16
// baseline (289.786 us; speedup 1.0000x reference)
//
#include <hip/hip_runtime.h>
#include <math.h>

#define BB 2
#define HH 8
#define SS 2048
#define DD 64
#define NBH (BB*HH)

typedef float f32x4 __attribute__((ext_vector_type(4)));
typedef short bf16x8 __attribute__((ext_vector_type(8)));
typedef short bf16x4 __attribute__((ext_vector_type(4)));

#define LOG2E 1.44269504f

static __device__ __forceinline__ short f2bf(float x) {
    unsigned u = __float_as_uint(x);
    u = (u + 0x7fffu + ((u >> 16) & 1u)) >> 16;
    return (short)u;
}

// ---- fused prep: blocks [0,512) transpose V -> bf16 Vt[bh][d][j];
//      blocks [512,1536) convert Q (scaled by 0.125*log2e) and K -> bf16 ----
__global__ __launch_bounds__(256) void prep_all(const float* __restrict__ Q,
                                                const float* __restrict__ K,
                                                const float* __restrict__ V,
                                                short* __restrict__ Qb,
                                                short* __restrict__ Kb,
                                                short* __restrict__ Vt)
{
    __shared__ short t[64][72];
    const int tid = threadIdx.x;
    if (blockIdx.x < 512) {
        const int jt = blockIdx.x & 31, bh = blockIdx.x >> 5;
        const int r  = tid >> 2;
        const int c4 = (tid & 3) * 16;
        const float* vb = V + ((size_t)bh * SS + (size_t)jt * 64) * DD;
        #pragma unroll
        for (int cc = 0; cc < 4; ++cc) {
            float4 v = *(const float4*)(vb + r * DD + c4 + cc * 4);
            t[c4 + cc*4 + 0][r] = f2bf(v.x);
            t[c4 + cc*4 + 1][r] = f2bf(v.y);
            t[c4 + cc*4 + 2][r] = f2bf(v.z);
            t[c4 + cc*4 + 3][r] = f2bf(v.w);
        }
        __syncthreads();
        short* ob = Vt + ((size_t)bh * DD + r) * SS + (size_t)jt * 64 + c4;
        *(bf16x8*)ob       = *(bf16x8*)&t[r][c4];
        *(bf16x8*)(ob + 8) = *(bf16x8*)&t[r][c4 + 8];
    } else {
        const float qs = 0.125f * LOG2E;   // exp2-domain scale
        const int n4 = NBH * SS * DD / 4;
        for (int idx = (blockIdx.x - 512) * 256 + tid; idx < n4; idx += 1024 * 256) {
            float4 q = ((const float4*)Q)[idx];
            float4 k = ((const float4*)K)[idx];
            bf16x4 qo, ko;
            qo[0] = f2bf(qs * q.x); qo[1] = f2bf(qs * q.y);
            qo[2] = f2bf(qs * q.z); qo[3] = f2bf(qs * q.w);
            ko[0] = f2bf(k.x); ko[1] = f2bf(k.y); ko[2] = f2bf(k.z); ko[3] = f2bf(k.w);
            ((bf16x4*)Qb)[idx] = qo;
            ((bf16x4*)Kb)[idx] = ko;
        }
    }
}

// ---- main: complementary PAIR of 32-row tiles {p, 63-p}, 16-wave key split ----
// 512 blocks x 1024 threads -> 2 blocks/CU, 32 waves/CU (100% cap), work
// identical for all blocks. Softmax in exp2 domain (scores*log2e <= ~9 << 128),
// no max subtraction; normalization folded into the exponent.
__global__ __launch_bounds__(1024, 8) void attn_main(
    const short* __restrict__ Qb, const short* __restrict__ Kb,
    const short* __restrict__ Vt,
    float* __restrict__ out, float* __restrict__ wts)
{
    // XCD-aware swizzle: 512 blocks, 8 XCDs, 64 consecutive per XCD.
    const int flat = blockIdx.x;
    const int wg   = (flat & 7) * 64 + (flat >> 3);
    const int bh   = wg >> 5;          // 0..15
    const int pr   = wg & 31;          // 0..31
    const int h    = bh & 7;

    const int tid  = threadIdx.x;
    const int wv   = tid >> 6;         // wave 0..15
    const int lane = tid & 63;
    const int g    = lane >> 4;
    const int c16  = lane & 15;

    __shared__ float smo[16][16][65];  // output merge, odd stride (66.6 KB)
    __shared__ float lred[16][2][16];

    const short* Kp = Kb + (size_t)bh * SS * DD;
    const short* Vp = Vt + (size_t)bh * DD * SS;

    const float slope2 = exp2f(-(float)(h + 1)) * LOG2E;   // ALiBi slope, exp2 domain

    // slot u = t*4+r  ->  key offset kk = 16t + 4g + r
    int kk8[8]; float offc[8];
    #pragma unroll
    for (int t = 0; t < 2; ++t)
        #pragma unroll
        for (int r = 0; r < 4; ++r) {
            kk8[t*4+r]  = 16*t + 4*g + r;
            offc[t*4+r] = slope2 * (float)(16*t + 4*g + r);
        }

    #pragma unroll 1
    for (int it = 0; it < 2; ++it) {
        const int qt     = (it == 0) ? pr : 63 - pr;
        const int q0     = qt * 32;
        const int nsteps = qt + 1;
        const int cover  = q0 + 32;

        const short* Qp = Qb + ((size_t)bh * SS + q0) * DD;
        float* wbase = wts + ((size_t)bh * SS + q0) * (size_t)SS;
        float* obase = out + ((size_t)bh * SS + q0) * DD;

        // ---- zero-fill weight columns >= cover (strict upper triangle) ----
        {
            const int n4 = (SS - cover) >> 2;
            const f32x4 z = {0.f, 0.f, 0.f, 0.f};
            for (int r = 0; r < 32; ++r) {
                float* wr = wbase + (size_t)r * SS + cover;
                for (int c = tid; c < n4; c += 1024) ((f32x4*)wr)[c] = z;
            }
        }

        // ---- Q fragments (2 q-halves x 2 dim-chunks) ----
        bf16x8 qf[2][2];
        #pragma unroll
        for (int qh = 0; qh < 2; ++qh)
            #pragma unroll
            for (int c = 0; c < 2; ++c)
                qf[qh][c] = *(const bf16x8*)(Qp + (size_t)(qh*16 + c16) * DD + c*32 + g*8);

        // ===== PASS 1: row denom (exp2 domain) =====
        float l[2] = {0.f, 0.f};
        for (int s = wv; s < nsteps; s += 16) {
            const int j0 = s * 32;
            bf16x8 kf[2][2];
            #pragma unroll
            for (int t = 0; t < 2; ++t)
                #pragma unroll
                for (int c = 0; c < 2; ++c)
                    kf[t][c] = *(const bf16x8*)(Kp + (size_t)(j0 + 16*t + c16) * DD + c*32 + g*8);

            f32x4 acc[2][2];
            #pragma unroll
            for (int qh = 0; qh < 2; ++qh)
                #pragma unroll
                for (int t = 0; t < 2; ++t)
                    acc[qh][t] = (f32x4){0.f, 0.f, 0.f, 0.f};
            #pragma unroll
            for (int qh = 0; qh < 2; ++qh)
                #pragma unroll
                for (int t = 0; t < 2; ++t)
                    #pragma unroll
                    for (int c = 0; c < 2; ++c)
                        acc[qh][t] = __builtin_amdgcn_mfma_f32_16x16x32_bf16(kf[t][c], qf[qh][c], acc[qh][t], 0, 0, 0);

            const bool diag = (s == qt);
            #pragma unroll
            for (int qh = 0; qh < 2; ++qh) {
                const int   irow = q0 + qh*16 + c16;
                const float sb   = slope2 * (float)(j0 - irow);
                const int   lim  = irow - j0;
                float ls = 0.f;
                #pragma unroll
                for (int u = 0; u < 8; ++u) {
                    float e = exp2f(acc[qh][u>>2][u&3] + sb + offc[u]);
                    if (diag) e = (kk8[u] <= lim) ? e : 0.f;
                    ls += e;
                }
                l[qh] += ls;
            }
        }
        #pragma unroll
        for (int qh = 0; qh < 2; ++qh) {
            l[qh] += __shfl_xor(l[qh], 16, 64);
            l[qh] += __shfl_xor(l[qh], 32, 64);
        }

        if (lane < 16) {
            #pragma unroll
            for (int qh = 0; qh < 2; ++qh) lred[wv][qh][lane] = l[qh];
        }
        __syncthreads();
        float lg2in[2];
        #pragma unroll
        for (int qh = 0; qh < 2; ++qh) {
            float lf = 0.f;
            #pragma unroll
            for (int w2 = 0; w2 < 16; ++w2) lf += lred[w2][qh][c16];
            lg2in[qh] = -__log2f(lf);    // fold normalization into the exponent
        }

        // ===== PASS 2: weights (direct cached stores) + PV =====
        f32x4 oacc[2][4];
        #pragma unroll
        for (int qh = 0; qh < 2; ++qh)
            #pragma unroll
            for (int d0 = 0; d0 < 4; ++d0) oacc[qh][d0] = (f32x4){0.f, 0.f, 0.f, 0.f};

        for (int s = wv; s < nsteps; s += 16) {
            const int j0 = s * 32;
            bf16x8 kf[2][2];
            #pragma unroll
            for (int t = 0; t < 2; ++t)
                #pragma unroll
                for (int c = 0; c < 2; ++c)
                    kf[t][c] = *(const bf16x8*)(Kp + (size_t)(j0 + 16*t + c16) * DD + c*32 + g*8);

            f32x4 acc[2][2];
            #pragma unroll
            for (int qh = 0; qh < 2; ++qh)
                #pragma unroll
                for (int t = 0; t < 2; ++t)
                    acc[qh][t] = (f32x4){0.f, 0.f, 0.f, 0.f};
            #pragma unroll
            for (int qh = 0; qh < 2; ++qh)
                #pragma unroll
                for (int t = 0; t < 2; ++t)
                    #pragma unroll
                    for (int c = 0; c < 2; ++c)
                        acc[qh][t] = __builtin_amdgcn_mfma_f32_16x16x32_bf16(kf[t][c], qf[qh][c], acc[qh][t], 0, 0, 0);

            const bool diag = (s == qt);
            bf16x8 wf[2];
            #pragma unroll
            for (int qh = 0; qh < 2; ++qh) {
                const int   irow = q0 + qh*16 + c16;
                const float sbw  = slope2 * (float)(j0 - irow) + lg2in[qh];
                const int   lim  = irow - j0;
                float w8[8];
                #pragma unroll
                for (int u = 0; u < 8; ++u) {
                    float e = exp2f(acc[qh][u>>2][u&3] + sbw + offc[u]);
                    if (diag) e = (kk8[u] <= lim) ? e : 0.f;
                    w8[u] = e;
                }
                // direct cached stores: row c16, lanes g=0..3 cover cols
                // [0,16)+[16,32) as contiguous 64B segments -> L2 write-combined.
                float* wr0 = wbase + (size_t)(qh*16 + c16) * SS + j0 + 4*g;
                *(f32x4*)wr0        = (f32x4){w8[0], w8[1], w8[2], w8[3]};
                *(f32x4*)(wr0 + 16) = (f32x4){w8[4], w8[5], w8[6], w8[7]};
                #pragma unroll
                for (int u = 0; u < 8; ++u) wf[qh][u] = f2bf(w8[u]);
            }

            // PV: A = V^T chunk (vectorized), B = P^T (regs)
            const short* vp = Vp + j0;
            #pragma unroll
            for (int d0 = 0; d0 < 4; ++d0) {
                const short* vr = vp + (size_t)(d0*16 + c16) * SS;
                bf16x4 a  = *(const bf16x4*)(vr + 4*g);
                bf16x4 b2 = *(const bf16x4*)(vr + 16 + 4*g);
                bf16x8 vf;
                vf[0]=a[0]; vf[1]=a[1]; vf[2]=a[2]; vf[3]=a[3];
                vf[4]=b2[0]; vf[5]=b2[1]; vf[6]=b2[2]; vf[7]=b2[3];
                #pragma unroll
                for (int qh = 0; qh < 2; ++qh)
                    oacc[qh][d0] = __builtin_amdgcn_mfma_f32_16x16x32_bf16(vf, wf[qh], oacc[qh][d0], 0, 0, 0);
            }
        }

        // ---- merge O^T partials across 16 waves (two 16-row chunks) ----
        __syncthreads();
        #pragma unroll
        for (int qh = 0; qh < 2; ++qh) {
            #pragma unroll
            for (int d0 = 0; d0 < 4; ++d0)
                *(f32x4*)&smo[wv][c16][d0*16 + 4*g] = oacc[qh][d0];
            __syncthreads();
            if (tid < 256) {
                int q = tid >> 4, dc = tid & 15;
                f32x4 r = {0.f, 0.f, 0.f, 0.f};
                #pragma unroll
                for (int w2 = 0; w2 < 16; ++w2) r += *(f32x4*)&smo[w2][q][dc * 4];
                *(f32x4*)(obase + (size_t)(qh*16 + q) * DD + dc * 4) = r;
            }
            __syncthreads();
        }
    }
}

extern "C" void kernel_launch(void* const* d_in, const int* in_sizes, int n_in,
                              void* d_out, int out_size, void* d_ws, size_t ws_size,
                              hipStream_t stream) {
    const float* Q = (const float*)d_in[0];
    const float* K = (const float*)d_in[1];
    const float* V = (const float*)d_in[2];
    // d_in[3] (mask) / d_in[4] (alibi_bias) are exact index functions — recomputed on the fly.

    float* out = (float*)d_out;                           // B*H*S*DV
    float* wts = out + (size_t)BB * HH * SS * DD;         // B*H*S*S

    const size_t n = (size_t)NBH * SS * DD;               // 2M elements
    short* Qb = (short*)d_ws;
    short* Kb = Qb + n;
    short* Vt = Kb + n;                                   // 12 MB total in ws

    prep_all<<<dim3(1536), dim3(256), 0, stream>>>(Q, K, V, Qb, Kb, Vt);

    attn_main<<<dim3(512), dim3(1024), 0, stream>>>(Qb, Kb, Vt, out, wts);
}

// Round 17
// 96.742 us; speedup vs baseline: 2.9954x; 2.9954x over previous
//
#include <hip/hip_runtime.h>
#include <math.h>

#define BB 2
#define HH 8
#define SS 2048
#define DD 64
#define NBH (BB*HH)

typedef float f32x4 __attribute__((ext_vector_type(4)));
typedef short bf16x8 __attribute__((ext_vector_type(8)));
typedef short bf16x4 __attribute__((ext_vector_type(4)));

#define LOG2E 1.44269504f

static __device__ __forceinline__ short f2bf(float x) {
    unsigned u = __float_as_uint(x);
    u = (u + 0x7fffu + ((u >> 16) & 1u)) >> 16;
    return (short)u;
}

// ---- fused prep: blocks [0,512) transpose V -> bf16 Vt[bh][d][j'] with
//      PERMUTED key order (j' groups each lane's 8 PV k-slots contiguously);
//      blocks [512,1536) convert Q (scaled by 0.125*log2e) and K -> bf16 ----
// Permutation within each 32-key block: position G*8+{0..7} holds keys
// {4G..4G+3, 16+4G..16+4G+3}  (G = lane k-group 0..3).
__global__ __launch_bounds__(256) void prep_all(const float* __restrict__ Q,
                                                const float* __restrict__ K,
                                                const float* __restrict__ V,
                                                short* __restrict__ Qb,
                                                short* __restrict__ Kb,
                                                short* __restrict__ Vt)
{
    __shared__ short t[64][72];
    const int tid = threadIdx.x;
    if (blockIdx.x < 512) {
        const int jt = blockIdx.x & 31, bh = blockIdx.x >> 5;
        const int r  = tid >> 2;
        const int c4 = (tid & 3) * 16;
        const float* vb = V + ((size_t)bh * SS + (size_t)jt * 64) * DD;
        #pragma unroll
        for (int cc = 0; cc < 4; ++cc) {
            float4 v = *(const float4*)(vb + r * DD + c4 + cc * 4);
            t[c4 + cc*4 + 0][r] = f2bf(v.x);
            t[c4 + cc*4 + 1][r] = f2bf(v.y);
            t[c4 + cc*4 + 2][r] = f2bf(v.z);
            t[c4 + cc*4 + 3][r] = f2bf(v.w);
        }
        __syncthreads();
        short* ob = Vt + ((size_t)bh * DD + r) * SS + (size_t)jt * 64;
        const int blk = (c4 >> 5) * 32;       // which 32-key sub-block
        const int Gb  = (c4 & 31) >> 3;       // starting k-group (0 or 2)
        #pragma unroll
        for (int m = 0; m < 2; ++m) {
            const int G = Gb + m;
            bf16x4 lo = *(bf16x4*)&t[r][blk + 4*G];
            bf16x4 hi = *(bf16x4*)&t[r][blk + 16 + 4*G];
            bf16x8 v8;
            v8[0]=lo[0]; v8[1]=lo[1]; v8[2]=lo[2]; v8[3]=lo[3];
            v8[4]=hi[0]; v8[5]=hi[1]; v8[6]=hi[2]; v8[7]=hi[3];
            *(bf16x8*)(ob + c4 + m*8) = v8;
        }
    } else {
        const float qs = 0.125f * LOG2E;   // exp2-domain scale
        const int n4 = NBH * SS * DD / 4;
        for (int idx = (blockIdx.x - 512) * 256 + tid; idx < n4; idx += 1024 * 256) {
            float4 q = ((const float4*)Q)[idx];
            float4 k = ((const float4*)K)[idx];
            bf16x4 qo, ko;
            qo[0] = f2bf(qs * q.x); qo[1] = f2bf(qs * q.y);
            qo[2] = f2bf(qs * q.z); qo[3] = f2bf(qs * q.w);
            ko[0] = f2bf(k.x); ko[1] = f2bf(k.y); ko[2] = f2bf(k.z); ko[3] = f2bf(k.w);
            ((bf16x4*)Qb)[idx] = qo;
            ((bf16x4*)Kb)[idx] = ko;
        }
    }
}

// ---- main: complementary PAIR of 32-row tiles {p, 63-p}, 8-wave key split ----
// 512 blocks x 512 threads, launch_bounds(512,4) -> VGPR<=128 (uses ~64).
// Per-block work identical for all blocks (65 steps x 2 passes).
// Softmax in exp2 domain, no max subtraction (scores*log2e <= ~9 << 128);
// normalization folded into the exponent.
__global__ __launch_bounds__(512, 4) void attn_main(
    const short* __restrict__ Qb, const short* __restrict__ Kb,
    const short* __restrict__ Vt,
    float* __restrict__ out, float* __restrict__ wts)
{
    // XCD-aware swizzle: 512 blocks, 8 XCDs, 64 consecutive per XCD.
    const int flat = blockIdx.x;
    const int wg   = (flat & 7) * 64 + (flat >> 3);
    const int bh   = wg >> 5;          // 0..15
    const int pr   = wg & 31;          // 0..31
    const int h    = bh & 7;

    const int tid  = threadIdx.x;
    const int wv   = tid >> 6;         // wave 0..7
    const int lane = tid & 63;
    const int g    = lane >> 4;
    const int c16  = lane & 15;

    __shared__ float smo[8][16][65];   // output merge, odd stride
    __shared__ float lred[8][2][16];

    const short* Kp = Kb + (size_t)bh * SS * DD;
    const short* Vp = Vt + (size_t)bh * DD * SS;

    const float slope2 = exp2f(-(float)(h + 1)) * LOG2E;   // ALiBi slope, exp2 domain

    // slot u = t*4+r  ->  key offset kk = 16t + 4g + r
    int kk8[8]; float offc[8];
    #pragma unroll
    for (int t = 0; t < 2; ++t)
        #pragma unroll
        for (int r = 0; r < 4; ++r) {
            kk8[t*4+r]  = 16*t + 4*g + r;
            offc[t*4+r] = slope2 * (float)(16*t + 4*g + r);
        }

    #pragma unroll 1
    for (int it = 0; it < 2; ++it) {
        const int qt     = (it == 0) ? pr : 63 - pr;
        const int q0     = qt * 32;
        const int nsteps = qt + 1;
        const int cover  = q0 + 32;

        const short* Qp = Qb + ((size_t)bh * SS + q0) * DD;
        float* wbase = wts + ((size_t)bh * SS + q0) * (size_t)SS;
        float* obase = out + ((size_t)bh * SS + q0) * DD;

        // ---- zero-fill weight columns >= cover (strict upper triangle) ----
        {
            const int n4 = (SS - cover) >> 2;
            const f32x4 z = {0.f, 0.f, 0.f, 0.f};
            for (int r = 0; r < 32; ++r) {
                float* wr = wbase + (size_t)r * SS + cover;
                for (int c = tid; c < n4; c += 512) ((f32x4*)wr)[c] = z;
            }
        }

        // ---- Q fragments (2 q-halves x 2 dim-chunks) ----
        bf16x8 qf[2][2];
        #pragma unroll
        for (int qh = 0; qh < 2; ++qh)
            #pragma unroll
            for (int c = 0; c < 2; ++c)
                qf[qh][c] = *(const bf16x8*)(Qp + (size_t)(qh*16 + c16) * DD + c*32 + g*8);

        // ===== PASS 1: row denom (exp2 domain) =====
        float l[2] = {0.f, 0.f};
        for (int s = wv; s < nsteps; s += 8) {
            const int j0 = s * 32;
            bf16x8 kf[2][2];
            #pragma unroll
            for (int t = 0; t < 2; ++t)
                #pragma unroll
                for (int c = 0; c < 2; ++c)
                    kf[t][c] = *(const bf16x8*)(Kp + (size_t)(j0 + 16*t + c16) * DD + c*32 + g*8);

            f32x4 acc[2][2];
            #pragma unroll
            for (int qh = 0; qh < 2; ++qh)
                #pragma unroll
                for (int t = 0; t < 2; ++t)
                    acc[qh][t] = (f32x4){0.f, 0.f, 0.f, 0.f};
            #pragma unroll
            for (int qh = 0; qh < 2; ++qh)
                #pragma unroll
                for (int t = 0; t < 2; ++t)
                    #pragma unroll
                    for (int c = 0; c < 2; ++c)
                        acc[qh][t] = __builtin_amdgcn_mfma_f32_16x16x32_bf16(kf[t][c], qf[qh][c], acc[qh][t], 0, 0, 0);

            const bool diag = (s == qt);
            #pragma unroll
            for (int qh = 0; qh < 2; ++qh) {
                const int   irow = q0 + qh*16 + c16;
                const float sb   = slope2 * (float)(j0 - irow);
                const int   lim  = irow - j0;
                float ls = 0.f;
                #pragma unroll
                for (int u = 0; u < 8; ++u) {
                    float e = exp2f(acc[qh][u>>2][u&3] + sb + offc[u]);
                    if (diag) e = (kk8[u] <= lim) ? e : 0.f;
                    ls += e;
                }
                l[qh] += ls;
            }
        }
        #pragma unroll
        for (int qh = 0; qh < 2; ++qh) {
            l[qh] += __shfl_xor(l[qh], 16, 64);
            l[qh] += __shfl_xor(l[qh], 32, 64);
        }

        if (lane < 16) {
            #pragma unroll
            for (int qh = 0; qh < 2; ++qh) lred[wv][qh][lane] = l[qh];
        }
        __syncthreads();
        float lg2in[2];
        #pragma unroll
        for (int qh = 0; qh < 2; ++qh) {
            float lf = 0.f;
            #pragma unroll
            for (int w2 = 0; w2 < 8; ++w2) lf += lred[w2][qh][c16];
            lg2in[qh] = -__log2f(lf);    // fold normalization into the exponent
        }

        // ===== PASS 2: weights (direct cached stores) + PV =====
        f32x4 oacc[2][4];
        #pragma unroll
        for (int qh = 0; qh < 2; ++qh)
            #pragma unroll
            for (int d0 = 0; d0 < 4; ++d0) oacc[qh][d0] = (f32x4){0.f, 0.f, 0.f, 0.f};

        for (int s = wv; s < nsteps; s += 8) {
            const int j0 = s * 32;
            bf16x8 kf[2][2];
            #pragma unroll
            for (int t = 0; t < 2; ++t)
                #pragma unroll
                for (int c = 0; c < 2; ++c)
                    kf[t][c] = *(const bf16x8*)(Kp + (size_t)(j0 + 16*t + c16) * DD + c*32 + g*8);

            f32x4 acc[2][2];
            #pragma unroll
            for (int qh = 0; qh < 2; ++qh)
                #pragma unroll
                for (int t = 0; t < 2; ++t)
                    acc[qh][t] = (f32x4){0.f, 0.f, 0.f, 0.f};
            #pragma unroll
            for (int qh = 0; qh < 2; ++qh)
                #pragma unroll
                for (int t = 0; t < 2; ++t)
                    #pragma unroll
                    for (int c = 0; c < 2; ++c)
                        acc[qh][t] = __builtin_amdgcn_mfma_f32_16x16x32_bf16(kf[t][c], qf[qh][c], acc[qh][t], 0, 0, 0);

            const bool diag = (s == qt);
            bf16x8 wf[2];
            #pragma unroll
            for (int qh = 0; qh < 2; ++qh) {
                const int   irow = q0 + qh*16 + c16;
                const float sbw  = slope2 * (float)(j0 - irow) + lg2in[qh];
                const int   lim  = irow - j0;
                float w8[8];
                #pragma unroll
                for (int u = 0; u < 8; ++u) {
                    float e = exp2f(acc[qh][u>>2][u&3] + sbw + offc[u]);
                    if (diag) e = (kk8[u] <= lim) ? e : 0.f;
                    w8[u] = e;
                }
                // direct cached stores: row c16, lanes g=0..3 cover cols
                // [0,16)+[16,32) as contiguous 64B segments -> L2 write-combined.
                float* wr0 = wbase + (size_t)(qh*16 + c16) * SS + j0 + 4*g;
                *(f32x4*)wr0        = (f32x4){w8[0], w8[1], w8[2], w8[3]};
                *(f32x4*)(wr0 + 16) = (f32x4){w8[4], w8[5], w8[6], w8[7]};
                #pragma unroll
                for (int u = 0; u < 8; ++u) wf[qh][u] = f2bf(w8[u]);
            }

            // PV: A = V^T chunk — single bf16x8 load thanks to permuted Vt
            const short* vp = Vp + j0;
            #pragma unroll
            for (int d0 = 0; d0 < 4; ++d0) {
                const short* vr = vp + (size_t)(d0*16 + c16) * SS;
                bf16x8 vf = *(const bf16x8*)(vr + 8*g);
                #pragma unroll
                for (int qh = 0; qh < 2; ++qh)
                    oacc[qh][d0] = __builtin_amdgcn_mfma_f32_16x16x32_bf16(vf, wf[qh], oacc[qh][d0], 0, 0, 0);
            }
        }

        // ---- merge O^T partials across 8 waves (two 16-row chunks) ----
        __syncthreads();
        #pragma unroll
        for (int qh = 0; qh < 2; ++qh) {
            #pragma unroll
            for (int d0 = 0; d0 < 4; ++d0)
                *(f32x4*)&smo[wv][c16][d0*16 + 4*g] = oacc[qh][d0];
            __syncthreads();
            if (tid < 256) {
                int q = tid >> 4, dc = tid & 15;
                f32x4 r = {0.f, 0.f, 0.f, 0.f};
                #pragma unroll
                for (int w2 = 0; w2 < 8; ++w2) r += *(f32x4*)&smo[w2][q][dc * 4];
                *(f32x4*)(obase + (size_t)(qh*16 + q) * DD + dc * 4) = r;
            }
            __syncthreads();
        }
    }
}

extern "C" void kernel_launch(void* const* d_in, const int* in_sizes, int n_in,
                              void* d_out, int out_size, void* d_ws, size_t ws_size,
                              hipStream_t stream) {
    const float* Q = (const float*)d_in[0];
    const float* K = (const float*)d_in[1];
    const float* V = (const float*)d_in[2];
    // d_in[3] (mask) / d_in[4] (alibi_bias) are exact index functions — recomputed on the fly.

    float* out = (float*)d_out;                           // B*H*S*DV
    float* wts = out + (size_t)BB * HH * SS * DD;         // B*H*S*S

    const size_t n = (size_t)NBH * SS * DD;               // 2M elements
    short* Qb = (short*)d_ws;
    short* Kb = Qb + n;
    short* Vt = Kb + n;                                   // 12 MB total in ws

    prep_all<<<dim3(1536), dim3(256), 0, stream>>>(Q, K, V, Qb, Kb, Vt);

    attn_main<<<dim3(512), dim3(512), 0, stream>>>(Qb, Kb, Vt, out, wts);
}